// Round 1
// baseline (2603.133 us; speedup 1.0000x reference)
//
#include <hip/hip_runtime.h>
#include <hip/hip_bf16.h>
#include <cmath>

// Problem constants
#define Bc   32
#define Sc_  512
#define Hc   768
#define NHc  12
#define DHc  64
#define Mc   (Bc * Sc_)   // 16384 tokens

// ---------------------------------------------------------------------------
// Kernel 1: fused QKV projection GEMM.
//   Y = X @ W^T + bias,  X:[M,H], W:[H,H] (torch Linear => Y[m,n]=sum_k X[m,k]*W[n,k])
//   grid.z in {0,1,2} selects (Wq,bq)/(Wk,bk)/(Wv,bv); output written head-split
//   into ws as [3][B][NH][S][DH] fp32.
// 64x64 tile, BK=16, 256 threads, 4x4 acc per thread.
// ---------------------------------------------------------------------------
__global__ __launch_bounds__(256) void qkv_gemm(
    const float* __restrict__ X,
    const float* __restrict__ Wq, const float* __restrict__ bq,
    const float* __restrict__ Wk, const float* __restrict__ bk,
    const float* __restrict__ Wv, const float* __restrict__ bv,
    float* __restrict__ qkv)
{
    const int z = blockIdx.z;
    const float* __restrict__ W    = (z == 0) ? Wq : (z == 1) ? Wk : Wv;
    const float* __restrict__ bias = (z == 0) ? bq : (z == 1) ? bk : bv;
    float* __restrict__ out = qkv + (size_t)z * Mc * Hc;

    // k-major LDS tiles, padded stride 68 (68%32=4 -> conflict-free float4 reads)
    __shared__ float As[16][68];
    __shared__ float Bs[16][68];

    const int tid = threadIdx.x;
    const int tx = tid & 15;        // output col group
    const int ty = tid >> 4;        // output row group
    const int m0 = blockIdx.x * 64;
    const int n0 = blockIdx.y * 64;

    const int lr = tid >> 2;        // 0..63: tile row for loading
    const int lk = (tid & 3) * 4;   // 0,4,8,12: k offset for loading

    float acc[4][4] = {};

    for (int k0 = 0; k0 < Hc; k0 += 16) {
        float4 av = *(const float4*)&X[(size_t)(m0 + lr) * Hc + k0 + lk];
        float4 wv = *(const float4*)&W[(size_t)(n0 + lr) * Hc + k0 + lk];
        As[lk + 0][lr] = av.x; As[lk + 1][lr] = av.y;
        As[lk + 2][lr] = av.z; As[lk + 3][lr] = av.w;
        Bs[lk + 0][lr] = wv.x; Bs[lk + 1][lr] = wv.y;
        Bs[lk + 2][lr] = wv.z; Bs[lk + 3][lr] = wv.w;
        __syncthreads();
        #pragma unroll
        for (int kk = 0; kk < 16; ++kk) {
            float4 a4 = *(const float4*)&As[kk][ty * 4];
            float4 b4 = *(const float4*)&Bs[kk][tx * 4];
            float a[4] = {a4.x, a4.y, a4.z, a4.w};
            float b[4] = {b4.x, b4.y, b4.z, b4.w};
            #pragma unroll
            for (int i = 0; i < 4; ++i)
                #pragma unroll
                for (int j = 0; j < 4; ++j)
                    acc[i][j] += a[i] * b[j];
        }
        __syncthreads();
    }

    // Epilogue: add bias, scatter into [B][NH][S][DH]. Tile spans exactly one head.
    const int h = n0 >> 6;          // n0 % 64 == 0
    const int dcol = tx * 4;        // d = dcol..dcol+3
    float4 bia = *(const float4*)&bias[n0 + dcol];
    #pragma unroll
    for (int i = 0; i < 4; ++i) {
        int m = m0 + ty * 4 + i;
        int b = m >> 9;             // / 512
        int s = m & 511;
        size_t dst = (((size_t)(b * NHc + h)) * Sc_ + s) * DHc + dcol;
        float4 o;
        o.x = acc[i][0] + bia.x;
        o.y = acc[i][1] + bia.y;
        o.z = acc[i][2] + bia.z;
        o.w = acc[i][3] + bia.w;
        *(float4*)&out[dst] = o;
    }
}

// ---------------------------------------------------------------------------
// Kernel 2: attention per (b, h, 16-query tile).
//   Phase 1: scores tile 16x512 in LDS (K staged through LDS in 64-key blocks)
//   Phase 2: softmax (max/sum via width-16 shfl_xor); keep 1/sum in register
//   Phase 3: ctx = P@V (V staged through same LDS buffer), tanh epilogue
// ---------------------------------------------------------------------------
__global__ __launch_bounds__(256) void attn(
    const float* __restrict__ qkv, float* __restrict__ out)
{
    const int b  = blockIdx.z;
    const int h  = blockIdx.y;
    const int q0 = blockIdx.x * 16;

    const size_t head_off = ((size_t)(b * NHc + h)) * Sc_ * DHc;
    const float* __restrict__ Q = qkv + head_off;
    const float* __restrict__ K = qkv + (size_t)1 * Mc * Hc + head_off;
    const float* __restrict__ V = qkv + (size_t)2 * Mc * Hc + head_off;

    __shared__ float Qs[16][68];     // pad 68: qi-stride bank-shifted
    __shared__ float KVs[64][68];    // shared between K and V phases
    __shared__ float Sc[16][520];    // pad 520 (520%32=8)

    const int tid = threadIdx.x;
    const int qi = tid >> 4;         // 0..15 query row
    const int kg = tid & 15;         // 0..15 key-group / d-group

    // Load Q tile (16x64): one float4 per thread
    {
        int r = tid >> 4, c = (tid & 15) * 4;
        *(float4*)&Qs[r][c] = *(const float4*)&Q[(size_t)(q0 + r) * DHc + c];
    }
    __syncthreads();

    // ---- Phase 1: scores ----
    for (int kb = 0; kb < Sc_; kb += 64) {
        #pragma unroll
        for (int it = 0; it < 4; ++it) {
            int f = tid + it * 256;          // float4 index 0..1023
            int r = f >> 4, c = (f & 15) * 4;
            *(float4*)&KVs[r][c] = *(const float4*)&K[(size_t)(kb + r) * DHc + c];
        }
        __syncthreads();
        float s[4] = {0.f, 0.f, 0.f, 0.f};
        #pragma unroll
        for (int d = 0; d < 64; d += 4) {
            float4 qv = *(const float4*)&Qs[qi][d];
            #pragma unroll
            for (int j = 0; j < 4; ++j) {
                float4 kv = *(const float4*)&KVs[kg * 4 + j][d];
                s[j] += qv.x * kv.x + qv.y * kv.y + qv.z * kv.z + qv.w * kv.w;
            }
        }
        #pragma unroll
        for (int j = 0; j < 4; ++j)
            Sc[qi][kb + kg * 4 + j] = s[j] * 0.125f;   // 1/sqrt(64)
        __syncthreads();
    }

    // ---- Phase 2: softmax over 512 cols; 16 threads per row ----
    float mx = -1e30f;
    for (int j = 0; j < 32; ++j) mx = fmaxf(mx, Sc[qi][kg + 16 * j]);
    #pragma unroll
    for (int w = 1; w < 16; w <<= 1) mx = fmaxf(mx, __shfl_xor(mx, w));
    float sum = 0.f;
    for (int j = 0; j < 32; ++j) {
        float p = __expf(Sc[qi][kg + 16 * j] - mx);
        Sc[qi][kg + 16 * j] = p;     // store un-normalized
        sum += p;
    }
    #pragma unroll
    for (int w = 1; w < 16; w <<= 1) sum += __shfl_xor(sum, w);
    const float inv = 1.0f / sum;    // same (qi) threads do PV below
    __syncthreads();

    // ---- Phase 3: ctx = P @ V ----
    float c4[4] = {0.f, 0.f, 0.f, 0.f};  // ctx[qi][kg*4 .. +3]
    for (int kb = 0; kb < Sc_; kb += 64) {
        #pragma unroll
        for (int it = 0; it < 4; ++it) {
            int f = tid + it * 256;
            int r = f >> 4, c = (f & 15) * 4;
            *(float4*)&KVs[r][c] = *(const float4*)&V[(size_t)(kb + r) * DHc + c];
        }
        __syncthreads();
        for (int kk = 0; kk < 64; ++kk) {
            float p = Sc[qi][kb + kk];                 // broadcast within row
            float4 vv = *(const float4*)&KVs[kk][kg * 4];
            c4[0] += p * vv.x; c4[1] += p * vv.y;
            c4[2] += p * vv.z; c4[3] += p * vv.w;
        }
        __syncthreads();
    }

    // ---- Epilogue: normalize, tanh, merge heads ----
    size_t o = (((size_t)b) * Sc_ + (q0 + qi)) * Hc + h * DHc + kg * 4;
    float4 r;
    r.x = tanhf(c4[0] * inv);
    r.y = tanhf(c4[1] * inv);
    r.z = tanhf(c4[2] * inv);
    r.w = tanhf(c4[3] * inv);
    *(float4*)&out[o] = r;
}

extern "C" void kernel_launch(void* const* d_in, const int* in_sizes, int n_in,
                              void* d_out, int out_size, void* d_ws, size_t ws_size,
                              hipStream_t stream) {
    const float* X  = (const float*)d_in[0];
    const float* Wq = (const float*)d_in[1];
    const float* bq = (const float*)d_in[2];
    const float* Wk = (const float*)d_in[3];
    const float* bk = (const float*)d_in[4];
    const float* Wv = (const float*)d_in[5];
    const float* bv = (const float*)d_in[6];
    float* out = (float*)d_out;
    float* qkv = (float*)d_ws;   // [3][B][NH][S][DH] fp32 = 144 MB

    dim3 g1(Mc / 64, Hc / 64, 3);   // 256 x 12 x 3
    qkv_gemm<<<g1, 256, 0, stream>>>(X, Wq, bq, Wk, bk, Wv, bv, qkv);

    dim3 g2(Sc_ / 16, NHc, Bc);     // 32 x 12 x 32
    attn<<<g2, 256, 0, stream>>>(qkv, out);
}

// Round 2
// 1030.789 us; speedup vs baseline: 2.5254x; 2.5254x over previous
//
#include <hip/hip_runtime.h>
#include <hip/hip_bf16.h>
#include <cmath>

// Problem constants
#define Bc   32
#define Sc_  512
#define Hc   768
#define NHc  12
#define DHc  64
#define Mc   (Bc * Sc_)   // 16384 tokens

typedef __attribute__((ext_vector_type(8))) short short8v;   // 8 bf16 (4 VGPRs)
typedef __attribute__((ext_vector_type(4))) float f32x4;     // MFMA acc

static __device__ __forceinline__ ushort f2b(float f) {
    __hip_bfloat16 h = __float2bfloat16(f);
    return *reinterpret_cast<ushort*>(&h);
}

// ---------------------------------------------------------------------------
// Kernel 1: fused QKV projection GEMM (fp32 compute, bf16 output).
//   Y = X @ W^T + bias. z=0 -> Q bf16 [B][NH][S][DH]; z=1 -> K same;
//   z=2 -> V TRANSPOSED bf16 [B][NH][DH][S] (so attn B-frags are contiguous).
// ---------------------------------------------------------------------------
__global__ __launch_bounds__(256) void qkv_gemm(
    const float* __restrict__ X,
    const float* __restrict__ Wq, const float* __restrict__ bq,
    const float* __restrict__ Wk, const float* __restrict__ bk,
    const float* __restrict__ Wv, const float* __restrict__ bv,
    ushort* __restrict__ Qb, ushort* __restrict__ Kb, ushort* __restrict__ Vt)
{
    const int z = blockIdx.z;
    const float* __restrict__ W    = (z == 0) ? Wq : (z == 1) ? Wk : Wv;
    const float* __restrict__ bias = (z == 0) ? bq : (z == 1) ? bk : bv;

    __shared__ float As[16][68];
    __shared__ float Bs[16][68];

    const int tid = threadIdx.x;
    const int tx = tid & 15;
    const int ty = tid >> 4;
    const int m0 = blockIdx.x * 64;
    const int n0 = blockIdx.y * 64;

    const int lr = tid >> 2;
    const int lk = (tid & 3) * 4;

    float acc[4][4] = {};

    for (int k0 = 0; k0 < Hc; k0 += 16) {
        float4 av = *(const float4*)&X[(size_t)(m0 + lr) * Hc + k0 + lk];
        float4 wv = *(const float4*)&W[(size_t)(n0 + lr) * Hc + k0 + lk];
        As[lk + 0][lr] = av.x; As[lk + 1][lr] = av.y;
        As[lk + 2][lr] = av.z; As[lk + 3][lr] = av.w;
        Bs[lk + 0][lr] = wv.x; Bs[lk + 1][lr] = wv.y;
        Bs[lk + 2][lr] = wv.z; Bs[lk + 3][lr] = wv.w;
        __syncthreads();
        #pragma unroll
        for (int kk = 0; kk < 16; ++kk) {
            float4 a4 = *(const float4*)&As[kk][ty * 4];
            float4 b4 = *(const float4*)&Bs[kk][tx * 4];
            float a[4] = {a4.x, a4.y, a4.z, a4.w};
            float b[4] = {b4.x, b4.y, b4.z, b4.w};
            #pragma unroll
            for (int i = 0; i < 4; ++i)
                #pragma unroll
                for (int j = 0; j < 4; ++j)
                    acc[i][j] += a[i] * b[j];
        }
        __syncthreads();
    }

    const int h = n0 >> 6;          // tile spans exactly one head (n0 % 64 == 0)
    const int dcol = tx * 4;
    float4 bia4 = *(const float4*)&bias[n0 + dcol];
    float bia[4] = {bia4.x, bia4.y, bia4.z, bia4.w};

    if (z < 2) {
        ushort* __restrict__ outp = (z == 0) ? Qb : Kb;
        #pragma unroll
        for (int i = 0; i < 4; ++i) {
            int m = m0 + ty * 4 + i;
            int bb = m >> 9, s = m & 511;
            size_t dst = (((size_t)(bb * NHc + h)) * Sc_ + s) * DHc + dcol;
            ushort4 o;
            o.x = f2b(acc[i][0] + bia[0]);
            o.y = f2b(acc[i][1] + bia[1]);
            o.z = f2b(acc[i][2] + bia[2]);
            o.w = f2b(acc[i][3] + bia[3]);
            *(ushort4*)&outp[dst] = o;
        }
    } else {
        #pragma unroll
        for (int i = 0; i < 4; ++i) {
            int m = m0 + ty * 4 + i;
            int bb = m >> 9, s = m & 511;
            #pragma unroll
            for (int j = 0; j < 4; ++j) {
                Vt[(((size_t)(bb * NHc + h)) * DHc + dcol + j) * Sc_ + s] =
                    f2b(acc[i][j] + bia[j]);
            }
        }
    }
}

// ---------------------------------------------------------------------------
// Kernel 2: flash-style attention, bf16 MFMA 16x16x32.
//   Block = 4 waves = 64 queries; wave owns 16 queries; loops 8 k-blocks of 64.
//   QK^T: A=Q (lane reads Q[q0+l16][quad*8..+7]), B=K (K[key][quad*8..+7]).
//   C/D layout: col=lane&15, row=quad*4+reg (m89-verified).
//   P: C-layout -> LDS (bf16, wave-private) -> A-layout for PV.
//   PV: B=V^T (Vt[d][quad*8..+7 keys]) contiguous.
// ---------------------------------------------------------------------------
__global__ __launch_bounds__(256) void attn_mfma(
    const ushort* __restrict__ Qb, const ushort* __restrict__ Kb,
    const ushort* __restrict__ Vt, float* __restrict__ out)
{
    const int b = blockIdx.z, h = blockIdx.y;
    const int wave = threadIdx.x >> 6;
    const int lane = threadIdx.x & 63;
    const int quad = lane >> 4, l16 = lane & 15;
    const int q0 = blockIdx.x * 64 + wave * 16;

    const size_t ho = ((size_t)(b * NHc + h)) * Sc_ * DHc;
    const ushort* __restrict__ Q = Qb + ho;
    const ushort* __restrict__ K = Kb + ho;
    const ushort* __restrict__ V = Vt + ((size_t)(b * NHc + h)) * DHc * Sc_;

    __shared__ __align__(16) ushort Plds[4][16][72];   // wave-private P tile

    const short8v aq0 = *(const short8v*)&Q[(size_t)(q0 + l16) * DHc + quad * 8];
    const short8v aq1 = *(const short8v*)&Q[(size_t)(q0 + l16) * DHc + 32 + quad * 8];

    float m_r[4], l_r[4];
    f32x4 o[4];
    #pragma unroll
    for (int r = 0; r < 4; ++r) { m_r[r] = -1e30f; l_r[r] = 0.f; }
    #pragma unroll
    for (int t = 0; t < 4; ++t) o[t] = (f32x4)(0.f);

    for (int kb0 = 0; kb0 < Sc_; kb0 += 64) {
        // ---- S = Q K^T (raw, scale folded later) ----
        f32x4 sa[4];
        #pragma unroll
        for (int t = 0; t < 4; ++t) sa[t] = (f32x4)(0.f);
        #pragma unroll
        for (int t = 0; t < 4; ++t) {
            const ushort* kp = &K[(size_t)(kb0 + t * 16 + l16) * DHc];
            short8v bk0 = *(const short8v*)&kp[quad * 8];
            short8v bk1 = *(const short8v*)&kp[32 + quad * 8];
            sa[t] = __builtin_amdgcn_mfma_f32_16x16x32_bf16(aq0, bk0, sa[t], 0, 0, 0);
            sa[t] = __builtin_amdgcn_mfma_f32_16x16x32_bf16(aq1, bk1, sa[t], 0, 0, 0);
        }
        // ---- online softmax (rows = quad*4+r, cols across 16 lanes x 4 tiles) ----
        float alpha[4];
        #pragma unroll
        for (int r = 0; r < 4; ++r) {
            float mx = fmaxf(fmaxf(sa[0][r], sa[1][r]), fmaxf(sa[2][r], sa[3][r]));
            mx = fmaxf(mx, __shfl_xor(mx, 1));
            mx = fmaxf(mx, __shfl_xor(mx, 2));
            mx = fmaxf(mx, __shfl_xor(mx, 4));
            mx = fmaxf(mx, __shfl_xor(mx, 8));
            mx *= 0.125f;                       // 1/sqrt(DH), monotone so after max
            float mnew = fmaxf(m_r[r], mx);
            alpha[r] = __expf(m_r[r] - mnew);
            m_r[r] = mnew;
        }
        float rs[4] = {0.f, 0.f, 0.f, 0.f};
        #pragma unroll
        for (int t = 0; t < 4; ++t) {
            #pragma unroll
            for (int r = 0; r < 4; ++r) {
                float p = __expf(sa[t][r] * 0.125f - m_r[r]);
                rs[r] += p;
                Plds[wave][quad * 4 + r][t * 16 + l16] = f2b(p);
            }
        }
        #pragma unroll
        for (int r = 0; r < 4; ++r) {
            float s = rs[r];
            s += __shfl_xor(s, 1);
            s += __shfl_xor(s, 2);
            s += __shfl_xor(s, 4);
            s += __shfl_xor(s, 8);
            l_r[r] = l_r[r] * alpha[r] + s;
            #pragma unroll
            for (int t = 0; t < 4; ++t) o[t][r] *= alpha[r];
        }
        // ---- P (A-layout) from LDS; PV ----
        short8v ap0 = *(const short8v*)&Plds[wave][l16][quad * 8];
        short8v ap1 = *(const short8v*)&Plds[wave][l16][32 + quad * 8];
        #pragma unroll
        for (int t2 = 0; t2 < 4; ++t2) {
            const ushort* vp = &V[(size_t)(t2 * 16 + l16) * Sc_ + kb0];
            short8v bv0 = *(const short8v*)&vp[quad * 8];
            short8v bv1 = *(const short8v*)&vp[32 + quad * 8];
            o[t2] = __builtin_amdgcn_mfma_f32_16x16x32_bf16(ap0, bv0, o[t2], 0, 0, 0);
            o[t2] = __builtin_amdgcn_mfma_f32_16x16x32_bf16(ap1, bv1, o[t2], 0, 0, 0);
        }
    }

    // ---- epilogue: normalize, tanh, merge heads ----
    #pragma unroll
    for (int r = 0; r < 4; ++r) {
        float inv = 1.0f / l_r[r];
        int q = q0 + quad * 4 + r;
        size_t base = ((size_t)b * Sc_ + q) * Hc + h * DHc;
        #pragma unroll
        for (int t2 = 0; t2 < 4; ++t2)
            out[base + t2 * 16 + l16] = tanhf(o[t2][r] * inv);
    }
}

extern "C" void kernel_launch(void* const* d_in, const int* in_sizes, int n_in,
                              void* d_out, int out_size, void* d_ws, size_t ws_size,
                              hipStream_t stream) {
    const float* X  = (const float*)d_in[0];
    const float* Wq = (const float*)d_in[1];
    const float* bq = (const float*)d_in[2];
    const float* Wk = (const float*)d_in[3];
    const float* bk = (const float*)d_in[4];
    const float* Wv = (const float*)d_in[5];
    const float* bv = (const float*)d_in[6];
    float* out = (float*)d_out;

    ushort* Qb = (ushort*)d_ws;                       // [B][NH][S][DH] bf16
    ushort* Kb = Qb + (size_t)Mc * Hc;                // [B][NH][S][DH] bf16
    ushort* Vt = Kb + (size_t)Mc * Hc;                // [B][NH][DH][S] bf16

    dim3 g1(Mc / 64, Hc / 64, 3);
    qkv_gemm<<<g1, 256, 0, stream>>>(X, Wq, bq, Wk, bk, Wv, bv, Qb, Kb, Vt);

    dim3 g2(Sc_ / 64, NHc, Bc);     // 8 x 12 x 32
    attn_mfma<<<g2, 256, 0, stream>>>(Qb, Kb, Vt, out);
}

// Round 3
// 370.498 us; speedup vs baseline: 7.0260x; 2.7822x over previous
//
#include <hip/hip_runtime.h>
#include <hip/hip_bf16.h>
#include <cmath>

// Problem constants
#define Bc   32
#define Sc_  512
#define Hc   768
#define NHc  12
#define DHc  64
#define Mc   (Bc * Sc_)     // 16384 tokens
#define Ntot (3 * Hc)       // 2304 fused output cols (Q|K|V)

typedef __attribute__((ext_vector_type(8))) short short8v;   // 8 bf16 (4 VGPRs)
typedef __attribute__((ext_vector_type(8))) unsigned short ushort8v;
typedef __attribute__((ext_vector_type(4))) float f32x4;     // MFMA acc

static __device__ __forceinline__ ushort f2b(float f) {
    __hip_bfloat16 h = __float2bfloat16(f);
    return *reinterpret_cast<ushort*>(&h);
}

// async global->LDS, 16B per lane. HW writes lane i to (wave-uniform lds)+i*16B.
static __device__ __forceinline__ void gl2lds(const ushort* g, ushort* l) {
    __builtin_amdgcn_global_load_lds(
        (const __attribute__((address_space(1))) unsigned int*)g,
        (__attribute__((address_space(3))) unsigned int*)l, 16, 0, 0);
}

// ---------------------------------------------------------------------------
// Kernel 0: convert fp32 -> bf16, tiled layout for MFMA staging.
//   Xt: [m/128][k/8][m%128][8] bf16   (m in [0,16384), k in [0,768))
//   Wt: [n/128][k/8][n%128][8] bf16   (n in [0,2304): Wq rows | Wk | Wv)
//   bbp: [2304] fp32 concatenated biases
// Reads coalesced (consecutive tid -> consecutive k-chunk of same row).
// ---------------------------------------------------------------------------
#define NXC (Mc * 96)        // 16384*96 X chunks of 8
#define NWC (Ntot * 96)      // 2304*96 W chunks
__global__ __launch_bounds__(256) void convert_pack(
    const float* __restrict__ X,
    const float* __restrict__ Wq, const float* __restrict__ Wk,
    const float* __restrict__ Wv,
    const float* __restrict__ bq, const float* __restrict__ bk,
    const float* __restrict__ bv,
    ushort* __restrict__ Xt, ushort* __restrict__ Wt, float* __restrict__ bbp)
{
    int tid = blockIdx.x * 256 + threadIdx.x;
    if (tid < NXC) {
        int kc   = tid % 96;
        int m    = tid / 96;            // 0..16383
        int mblk = m >> 7, mrow = m & 127;
        const float* src = X + (size_t)m * Hc + kc * 8;
        float4 f0 = *(const float4*)&src[0];
        float4 f1 = *(const float4*)&src[4];
        ushort8v o;
        o[0] = f2b(f0.x); o[1] = f2b(f0.y); o[2] = f2b(f0.z); o[3] = f2b(f0.w);
        o[4] = f2b(f1.x); o[5] = f2b(f1.y); o[6] = f2b(f1.z); o[7] = f2b(f1.w);
        *(ushort8v*)&Xt[((size_t)(mblk * 96 + kc)) * 1024 + mrow * 8] = o;
    } else if (tid < NXC + NWC) {
        int t2 = tid - NXC;
        int kc   = t2 % 96;
        int n    = t2 / 96;             // 0..2303
        int nblk = n >> 7, nrow = n & 127;
        int z = n / Hc, nn = n - z * Hc;
        const float* W = (z == 0) ? Wq : (z == 1) ? Wk : Wv;
        const float* src = W + (size_t)nn * Hc + kc * 8;
        float4 f0 = *(const float4*)&src[0];
        float4 f1 = *(const float4*)&src[4];
        ushort8v o;
        o[0] = f2b(f0.x); o[1] = f2b(f0.y); o[2] = f2b(f0.z); o[3] = f2b(f0.w);
        o[4] = f2b(f1.x); o[5] = f2b(f1.y); o[6] = f2b(f1.z); o[7] = f2b(f1.w);
        *(ushort8v*)&Wt[((size_t)(nblk * 96 + kc)) * 1024 + nrow * 8] = o;
    } else if (tid < NXC + NWC + Ntot) {
        int i = tid - NXC - NWC;
        int z = i / Hc, nn = i - z * Hc;
        bbp[i] = ((z == 0) ? bq : (z == 1) ? bk : bv)[nn];
    }
}

// ---------------------------------------------------------------------------
// Kernel 1: fused QKV projection, bf16 MFMA 16x16x32 (m97 structure).
//   C[m,n] = sum_k X[m,k] * Wcat[n,k] + bb[n];  M=16384, N=2304, K=768.
//   128x128 tile, BK=32, 4 waves, each wave 64x64 = 4x4 accumulators.
//   LDS tiles chunk-major [kchunk 0..3][row 0..127][8] -> 2-way-only bank
//   aliasing on ds_read_b128, and staging is one contiguous 8KB global range.
//   Epilogue: z=0 -> Qb [B][NH][S][DH]; z=1 -> Kb same; z=2 -> Vt [B][NH][DH][S].
// ---------------------------------------------------------------------------
__global__ __launch_bounds__(256) void qkv_mfma(
    const ushort* __restrict__ Xt, const ushort* __restrict__ Wt,
    const float* __restrict__ bbp,
    ushort* __restrict__ Qb, ushort* __restrict__ Kb, ushort* __restrict__ Vt)
{
    const int tid = threadIdx.x;
    const int wave = tid >> 6, lane = tid & 63;
    const int quad = lane >> 4, l16 = lane & 15;
    const int wr = wave >> 1, wc = wave & 1;
    const int m0 = blockIdx.x * 128;
    const int n0 = blockIdx.y * 128;

    __shared__ __align__(16) ushort As[4096];   // 8 KB: [4][128][8]
    __shared__ __align__(16) ushort Bs[4096];

    f32x4 acc[4][4];
    #pragma unroll
    for (int i = 0; i < 4; ++i)
        #pragma unroll
        for (int j = 0; j < 4; ++j) acc[i][j] = (f32x4)(0.f);

    // staging: 8 instrs cover 8KB; this wave's two 1KB slices at q=wave*2+{0,1}
    const ushort* gA = Xt + (size_t)blockIdx.x * (96 * 1024) + wave * 1024 + lane * 8;
    const ushort* gB = Wt + (size_t)blockIdx.y * (96 * 1024) + wave * 1024 + lane * 8;
    ushort* lA = As + wave * 1024;   // wave-uniform LDS base (lane scatter is HW)
    ushort* lB = Bs + wave * 1024;

    for (int t = 0; t < 24; ++t) {           // K = 24 * 32
        const ushort* ga = gA + t * 4096;
        const ushort* gb = gB + t * 4096;
        gl2lds(ga,       lA);
        gl2lds(ga + 512, lA + 512);
        gl2lds(gb,       lB);
        gl2lds(gb + 512, lB + 512);
        __syncthreads();

        short8v a[4], b[4];
        #pragma unroll
        for (int i = 0; i < 4; ++i)
            a[i] = *(const short8v*)&As[quad * 1024 + (wr * 64 + i * 16 + l16) * 8];
        #pragma unroll
        for (int j = 0; j < 4; ++j)
            b[j] = *(const short8v*)&Bs[quad * 1024 + (wc * 64 + j * 16 + l16) * 8];
        #pragma unroll
        for (int i = 0; i < 4; ++i)
            #pragma unroll
            for (int j = 0; j < 4; ++j)
                acc[i][j] = __builtin_amdgcn_mfma_f32_16x16x32_bf16(
                    a[i], b[j], acc[i][j], 0, 0, 0);
        __syncthreads();
    }

    // Epilogue. C layout per 16x16 tile: col=l16, row=quad*4+r.
    const int z = n0 / Hc;                   // 128-col tile within one projection
    #pragma unroll
    for (int j = 0; j < 4; ++j) {
        const int n  = n0 + wc * 64 + j * 16 + l16;
        const int nn = n - z * Hc;
        const int h  = nn >> 6, d = nn & 63;
        const float bias = bbp[n];
        #pragma unroll
        for (int i = 0; i < 4; ++i) {
            const int mbase = m0 + wr * 64 + i * 16 + quad * 4;   // + r
            const int bb = mbase >> 9;       // batch (tile never straddles)
            const int s0 = mbase & 511;
            if (z < 2) {
                ushort* outp = (z == 0) ? Qb : Kb;
                size_t base = (((size_t)(bb * NHc + h)) * Sc_ + s0) * DHc + d;
                #pragma unroll
                for (int r = 0; r < 4; ++r)
                    outp[base + (size_t)r * DHc] = f2b(acc[i][j][r] + bias);
            } else {
                // Vt[((bb*NH+h)*64 + d)*512 + s]; r -> consecutive s -> ushort4
                size_t base = (((size_t)(bb * NHc + h)) * DHc + d) * Sc_ + s0;
                ushort4 o;
                o.x = f2b(acc[i][j][0] + bias);
                o.y = f2b(acc[i][j][1] + bias);
                o.z = f2b(acc[i][j][2] + bias);
                o.w = f2b(acc[i][j][3] + bias);
                *(ushort4*)&Vt[base] = o;
            }
        }
    }
}

// ---------------------------------------------------------------------------
// Kernel 2: flash-style attention, bf16 MFMA 16x16x32 (unchanged from R2).
// ---------------------------------------------------------------------------
__global__ __launch_bounds__(256) void attn_mfma(
    const ushort* __restrict__ Qb, const ushort* __restrict__ Kb,
    const ushort* __restrict__ Vt, float* __restrict__ out)
{
    const int b = blockIdx.z, h = blockIdx.y;
    const int wave = threadIdx.x >> 6;
    const int lane = threadIdx.x & 63;
    const int quad = lane >> 4, l16 = lane & 15;
    const int q0 = blockIdx.x * 64 + wave * 16;

    const size_t ho = ((size_t)(b * NHc + h)) * Sc_ * DHc;
    const ushort* __restrict__ Q = Qb + ho;
    const ushort* __restrict__ K = Kb + ho;
    const ushort* __restrict__ V = Vt + ((size_t)(b * NHc + h)) * DHc * Sc_;

    __shared__ __align__(16) ushort Plds[4][16][72];   // wave-private P tile

    const short8v aq0 = *(const short8v*)&Q[(size_t)(q0 + l16) * DHc + quad * 8];
    const short8v aq1 = *(const short8v*)&Q[(size_t)(q0 + l16) * DHc + 32 + quad * 8];

    float m_r[4], l_r[4];
    f32x4 o[4];
    #pragma unroll
    for (int r = 0; r < 4; ++r) { m_r[r] = -1e30f; l_r[r] = 0.f; }
    #pragma unroll
    for (int t = 0; t < 4; ++t) o[t] = (f32x4)(0.f);

    for (int kb0 = 0; kb0 < Sc_; kb0 += 64) {
        f32x4 sa[4];
        #pragma unroll
        for (int t = 0; t < 4; ++t) sa[t] = (f32x4)(0.f);
        #pragma unroll
        for (int t = 0; t < 4; ++t) {
            const ushort* kp = &K[(size_t)(kb0 + t * 16 + l16) * DHc];
            short8v bk0 = *(const short8v*)&kp[quad * 8];
            short8v bk1 = *(const short8v*)&kp[32 + quad * 8];
            sa[t] = __builtin_amdgcn_mfma_f32_16x16x32_bf16(aq0, bk0, sa[t], 0, 0, 0);
            sa[t] = __builtin_amdgcn_mfma_f32_16x16x32_bf16(aq1, bk1, sa[t], 0, 0, 0);
        }
        float alpha[4];
        #pragma unroll
        for (int r = 0; r < 4; ++r) {
            float mx = fmaxf(fmaxf(sa[0][r], sa[1][r]), fmaxf(sa[2][r], sa[3][r]));
            mx = fmaxf(mx, __shfl_xor(mx, 1));
            mx = fmaxf(mx, __shfl_xor(mx, 2));
            mx = fmaxf(mx, __shfl_xor(mx, 4));
            mx = fmaxf(mx, __shfl_xor(mx, 8));
            mx *= 0.125f;
            float mnew = fmaxf(m_r[r], mx);
            alpha[r] = __expf(m_r[r] - mnew);
            m_r[r] = mnew;
        }
        float rs[4] = {0.f, 0.f, 0.f, 0.f};
        #pragma unroll
        for (int t = 0; t < 4; ++t) {
            #pragma unroll
            for (int r = 0; r < 4; ++r) {
                float p = __expf(sa[t][r] * 0.125f - m_r[r]);
                rs[r] += p;
                Plds[wave][quad * 4 + r][t * 16 + l16] = f2b(p);
            }
        }
        #pragma unroll
        for (int r = 0; r < 4; ++r) {
            float s = rs[r];
            s += __shfl_xor(s, 1);
            s += __shfl_xor(s, 2);
            s += __shfl_xor(s, 4);
            s += __shfl_xor(s, 8);
            l_r[r] = l_r[r] * alpha[r] + s;
            #pragma unroll
            for (int t = 0; t < 4; ++t) o[t][r] *= alpha[r];
        }
        short8v ap0 = *(const short8v*)&Plds[wave][l16][quad * 8];
        short8v ap1 = *(const short8v*)&Plds[wave][l16][32 + quad * 8];
        #pragma unroll
        for (int t2 = 0; t2 < 4; ++t2) {
            const ushort* vp = &V[(size_t)(t2 * 16 + l16) * Sc_ + kb0];
            short8v bv0 = *(const short8v*)&vp[quad * 8];
            short8v bv1 = *(const short8v*)&vp[32 + quad * 8];
            o[t2] = __builtin_amdgcn_mfma_f32_16x16x32_bf16(ap0, bv0, o[t2], 0, 0, 0);
            o[t2] = __builtin_amdgcn_mfma_f32_16x16x32_bf16(ap1, bv1, o[t2], 0, 0, 0);
        }
    }

    #pragma unroll
    for (int r = 0; r < 4; ++r) {
        float inv = 1.0f / l_r[r];
        int q = q0 + quad * 4 + r;
        size_t base = ((size_t)b * Sc_ + q) * Hc + h * DHc;
        #pragma unroll
        for (int t2 = 0; t2 < 4; ++t2)
            out[base + t2 * 16 + l16] = tanhf(o[t2][r] * inv);
    }
}

extern "C" void kernel_launch(void* const* d_in, const int* in_sizes, int n_in,
                              void* d_out, int out_size, void* d_ws, size_t ws_size,
                              hipStream_t stream) {
    const float* X  = (const float*)d_in[0];
    const float* Wq = (const float*)d_in[1];
    const float* bq = (const float*)d_in[2];
    const float* Wk = (const float*)d_in[3];
    const float* bk = (const float*)d_in[4];
    const float* Wv = (const float*)d_in[5];
    const float* bv = (const float*)d_in[6];
    float* out = (float*)d_out;

    // ws layout (bf16 ushorts unless noted)
    ushort* Qb  = (ushort*)d_ws;                       // [B][NH][S][DH]
    ushort* Kb  = Qb + (size_t)Mc * Hc;
    ushort* Vt  = Kb + (size_t)Mc * Hc;                // [B][NH][DH][S]
    ushort* Xt  = Vt + (size_t)Mc * Hc;                // tiled X
    ushort* Wt  = Xt + (size_t)Mc * Hc;                // tiled Wcat
    float*  bbp = (float*)(Wt + (size_t)Ntot * Hc);    // [2304] fp32

    {
        int total = NXC + NWC + Ntot;
        convert_pack<<<(total + 255) / 256, 256, 0, stream>>>(
            X, Wq, Wk, Wv, bq, bk, bv, Xt, Wt, bbp);
    }

    dim3 g1(Mc / 128, Ntot / 128);   // 128 x 18
    qkv_mfma<<<g1, 256, 0, stream>>>(Xt, Wt, bbp, Qb, Kb, Vt);

    dim3 g2(Sc_ / 64, NHc, Bc);      // 8 x 12 x 32
    attn_mfma<<<g2, 256, 0, stream>>>(Qb, Kb, Vt, out);
}

// Round 4
// 237.051 us; speedup vs baseline: 10.9813x; 1.5629x over previous
//
#include <hip/hip_runtime.h>
#include <hip/hip_bf16.h>
#include <cmath>

// Problem constants
#define Bc   32
#define Sc_  512
#define Hc   768
#define NHc  12
#define DHc  64
#define Mc   (Bc * Sc_)     // 16384 tokens
#define Ntot (3 * Hc)       // 2304 fused output cols (Q|K|V)

// 0.125 (1/sqrt(DH)) * log2(e): folded into Q so softmax is exp2(s)
#define QSCALE 0.18033688011112042f

typedef __attribute__((ext_vector_type(8))) short short8v;   // 8 bf16 (4 VGPRs)
typedef __attribute__((ext_vector_type(8))) unsigned short ushort8v;
typedef __attribute__((ext_vector_type(4))) float f32x4;     // MFMA acc

static __device__ __forceinline__ ushort f2b(float f) {
    __hip_bfloat16 h = __float2bfloat16(f);
    return *reinterpret_cast<ushort*>(&h);
}

// async global->LDS, 16B per lane. HW writes lane i to (wave-uniform lds)+i*16B.
static __device__ __forceinline__ void gl2lds(const ushort* g, ushort* l) {
    __builtin_amdgcn_global_load_lds(
        (const __attribute__((address_space(1))) unsigned int*)g,
        (__attribute__((address_space(3))) unsigned int*)l, 16, 0, 0);
}

// tanh(x) = 1 - 2/(exp2(2x*log2e)+1); exact at +/-inf via rcp(inf)=0
static __device__ __forceinline__ float fast_tanh(float x) {
    float e = __builtin_amdgcn_exp2f(x * 2.885390081777927f);
    return 1.0f - 2.0f * __builtin_amdgcn_rcpf(e + 1.0f);
}

// ---------------------------------------------------------------------------
// Kernel 0: convert fp32 -> bf16, tiled layout for MFMA staging (unchanged).
//   Xt: [m/128][k/8][m%128][8] bf16 ; Wt: [n/128][k/8][n%128][8] bf16
// ---------------------------------------------------------------------------
#define NXC (Mc * 96)
#define NWC (Ntot * 96)
__global__ __launch_bounds__(256) void convert_pack(
    const float* __restrict__ X,
    const float* __restrict__ Wq, const float* __restrict__ Wk,
    const float* __restrict__ Wv,
    const float* __restrict__ bq, const float* __restrict__ bk,
    const float* __restrict__ bv,
    ushort* __restrict__ Xt, ushort* __restrict__ Wt, float* __restrict__ bbp)
{
    int tid = blockIdx.x * 256 + threadIdx.x;
    if (tid < NXC) {
        int kc   = tid % 96;
        int m    = tid / 96;
        int mblk = m >> 7, mrow = m & 127;
        const float* src = X + (size_t)m * Hc + kc * 8;
        float4 f0 = *(const float4*)&src[0];
        float4 f1 = *(const float4*)&src[4];
        ushort8v o;
        o[0] = f2b(f0.x); o[1] = f2b(f0.y); o[2] = f2b(f0.z); o[3] = f2b(f0.w);
        o[4] = f2b(f1.x); o[5] = f2b(f1.y); o[6] = f2b(f1.z); o[7] = f2b(f1.w);
        *(ushort8v*)&Xt[((size_t)(mblk * 96 + kc)) * 1024 + mrow * 8] = o;
    } else if (tid < NXC + NWC) {
        int t2 = tid - NXC;
        int kc   = t2 % 96;
        int n    = t2 / 96;
        int nblk = n >> 7, nrow = n & 127;
        int z = n / Hc, nn = n - z * Hc;
        const float* W = (z == 0) ? Wq : (z == 1) ? Wk : Wv;
        const float* src = W + (size_t)nn * Hc + kc * 8;
        float4 f0 = *(const float4*)&src[0];
        float4 f1 = *(const float4*)&src[4];
        ushort8v o;
        o[0] = f2b(f0.x); o[1] = f2b(f0.y); o[2] = f2b(f0.z); o[3] = f2b(f0.w);
        o[4] = f2b(f1.x); o[5] = f2b(f1.y); o[6] = f2b(f1.z); o[7] = f2b(f1.w);
        *(ushort8v*)&Wt[((size_t)(nblk * 96 + kc)) * 1024 + nrow * 8] = o;
    } else if (tid < NXC + NWC + Ntot) {
        int i = tid - NXC - NWC;
        int z = i / Hc, nn = i - z * Hc;
        bbp[i] = ((z == 0) ? bq : (z == 1) ? bk : bv)[nn];
    }
}

// ---------------------------------------------------------------------------
// Kernel 1: fused QKV projection, bf16 MFMA (m97 structure, 128x128, BK=32).
// Epilogue layouts (per head, head = (b*NH+h), head stride S*DH = 32768):
//   Qb: [s][d] row-major, values pre-scaled by QSCALE
//   Kt: [kb=s/64][dchunk=d/8][s%64][8]      (A-frag-ready, 16B/lane)
//   Vt: [kb=s/64][keychunk=(s%64)/8][d][8]  (B-frag-ready, 16B/lane)
// ---------------------------------------------------------------------------
__global__ __launch_bounds__(256) void qkv_mfma(
    const ushort* __restrict__ Xt, const ushort* __restrict__ Wt,
    const float* __restrict__ bbp,
    ushort* __restrict__ Qb, ushort* __restrict__ Kt, ushort* __restrict__ Vt)
{
    const int tid = threadIdx.x;
    const int wave = tid >> 6, lane = tid & 63;
    const int quad = lane >> 4, l16 = lane & 15;
    const int wr = wave >> 1, wc = wave & 1;
    const int m0 = blockIdx.x * 128;
    const int n0 = blockIdx.y * 128;

    __shared__ __align__(16) ushort As[4096];
    __shared__ __align__(16) ushort Bs[4096];

    f32x4 acc[4][4];
    #pragma unroll
    for (int i = 0; i < 4; ++i)
        #pragma unroll
        for (int j = 0; j < 4; ++j) acc[i][j] = (f32x4)(0.f);

    const ushort* gA = Xt + (size_t)blockIdx.x * (96 * 1024) + wave * 1024 + lane * 8;
    const ushort* gB = Wt + (size_t)blockIdx.y * (96 * 1024) + wave * 1024 + lane * 8;
    ushort* lA = As + wave * 1024;
    ushort* lB = Bs + wave * 1024;

    for (int t = 0; t < 24; ++t) {
        const ushort* ga = gA + t * 4096;
        const ushort* gb = gB + t * 4096;
        gl2lds(ga,       lA);
        gl2lds(ga + 512, lA + 512);
        gl2lds(gb,       lB);
        gl2lds(gb + 512, lB + 512);
        __syncthreads();

        short8v a[4], b[4];
        #pragma unroll
        for (int i = 0; i < 4; ++i)
            a[i] = *(const short8v*)&As[quad * 1024 + (wr * 64 + i * 16 + l16) * 8];
        #pragma unroll
        for (int j = 0; j < 4; ++j)
            b[j] = *(const short8v*)&Bs[quad * 1024 + (wc * 64 + j * 16 + l16) * 8];
        #pragma unroll
        for (int i = 0; i < 4; ++i)
            #pragma unroll
            for (int j = 0; j < 4; ++j)
                acc[i][j] = __builtin_amdgcn_mfma_f32_16x16x32_bf16(
                    a[i], b[j], acc[i][j], 0, 0, 0);
        __syncthreads();
    }

    // Epilogue. C layout per 16x16 tile: col=l16, row=quad*4+r.
    const int z = n0 / Hc;
    #pragma unroll
    for (int j = 0; j < 4; ++j) {
        const int n  = n0 + wc * 64 + j * 16 + l16;
        const int nn = n - z * Hc;
        const int h  = nn >> 6, d = nn & 63;
        const float bias = bbp[n];
        #pragma unroll
        for (int i = 0; i < 4; ++i) {
            const int mbase = m0 + wr * 64 + i * 16 + quad * 4;   // s = mbase + r
            const int bb = mbase >> 9;
            const int s0 = mbase & 511;
            const size_t head = (size_t)(bb * NHc + h) * (Sc_ * DHc);
            if (z == 0) {
                size_t base = head + (size_t)s0 * DHc + d;
                #pragma unroll
                for (int r = 0; r < 4; ++r)
                    Qb[base + (size_t)r * DHc] = f2b((acc[i][j][r] + bias) * QSCALE);
            } else if (z == 1) {
                // Kt: kb*4096 + (d>>3)*512 + (s&63)*8 + (d&7); consecutive s -> +8
                size_t base = head + (s0 >> 6) * 4096 + (d >> 3) * 512
                            + (s0 & 63) * 8 + (d & 7);
                #pragma unroll
                for (int r = 0; r < 4; ++r)
                    Kt[base + r * 8] = f2b(acc[i][j][r] + bias);
            } else {
                // Vt: kb*4096 + ((s&63)>>3)*512 + d*8 + (s&7); r -> consecutive
                size_t base = head + (s0 >> 6) * 4096 + ((s0 & 63) >> 3) * 512
                            + d * 8 + (s0 & 7);
                ushort4 o;
                o.x = f2b(acc[i][j][0] + bias);
                o.y = f2b(acc[i][j][1] + bias);
                o.z = f2b(acc[i][j][2] + bias);
                o.w = f2b(acc[i][j][3] + bias);
                *(ushort4*)&Vt[base] = o;
            }
        }
    }
}

// ---------------------------------------------------------------------------
// Kernel 2: attention, no-max softmax (p = exp2(s~), scale folded into Q).
//   Block = 4 waves x 32 queries = 128 q. No __syncthreads (P wave-private).
//   S^T = mfma(A=K, B=Q): D[key=quad*4+r][q=l16] -> 4 consecutive keys per reg
//   P -> LDS (XOR-swizzled chunks, b64 writes / b128 reads, conflict-free)
//   O = mfma(A=P, B=V^T): D[q=quad*4+r][d=l16]
// ---------------------------------------------------------------------------
__global__ __launch_bounds__(256) void attn_mfma(
    const ushort* __restrict__ Qb, const ushort* __restrict__ Kt,
    const ushort* __restrict__ Vt, float* __restrict__ out)
{
    const int b = blockIdx.z, h = blockIdx.y;
    const int wave = threadIdx.x >> 6;
    const int lane = threadIdx.x & 63;
    const int quad = lane >> 4, l16 = lane & 15;
    const int q0 = blockIdx.x * 128 + wave * 32;
    const int sw = l16 & 7;                       // XOR swizzle key

    const size_t head = (size_t)(b * NHc + h) * (Sc_ * DHc);
    const ushort* __restrict__ Q = Qb + head;
    const ushort* __restrict__ K = Kt + head;
    const ushort* __restrict__ V = Vt + head;

    __shared__ __align__(16) ushort Plds[4][2][1024];   // wave-private

    short8v aq[2][2];
    #pragma unroll
    for (int u = 0; u < 2; ++u)
        #pragma unroll
        for (int hf = 0; hf < 2; ++hf)
            aq[u][hf] = *(const short8v*)
                &Q[(size_t)(q0 + u * 16 + l16) * DHc + hf * 32 + quad * 8];

    f32x4 o[2][4];
    #pragma unroll
    for (int u = 0; u < 2; ++u)
        #pragma unroll
        for (int t = 0; t < 4; ++t) o[u][t] = (f32x4)(0.f);
    float rs[2] = {0.f, 0.f};

    for (int kb = 0; kb < 8; ++kb) {
        const ushort* Kb_ = K + kb * 4096;
        const ushort* Vb_ = V + kb * 4096;

        // K A-frags (shared by both q-tiles)
        short8v kf[4][2];
        #pragma unroll
        for (int t = 0; t < 4; ++t) {
            kf[t][0] = *(const short8v*)&Kb_[quad * 512 + (t * 16 + l16) * 8];
            kf[t][1] = *(const short8v*)&Kb_[(4 + quad) * 512 + (t * 16 + l16) * 8];
        }

        // S^T: D[key part][q]
        f32x4 sa[2][4];
        #pragma unroll
        for (int u = 0; u < 2; ++u)
            #pragma unroll
            for (int t = 0; t < 4; ++t) {
                f32x4 s = __builtin_amdgcn_mfma_f32_16x16x32_bf16(
                    kf[t][0], aq[u][0], (f32x4)(0.f), 0, 0, 0);
                sa[u][t] = __builtin_amdgcn_mfma_f32_16x16x32_bf16(
                    kf[t][1], aq[u][1], s, 0, 0, 0);
            }

        // p = exp2(s~); accumulate row sums per lane (q = l16); pack to LDS
        #pragma unroll
        for (int u = 0; u < 2; ++u) {
            #pragma unroll
            for (int t = 0; t < 4; ++t) {
                float p0 = __builtin_amdgcn_exp2f(sa[u][t][0]);
                float p1 = __builtin_amdgcn_exp2f(sa[u][t][1]);
                float p2 = __builtin_amdgcn_exp2f(sa[u][t][2]);
                float p3 = __builtin_amdgcn_exp2f(sa[u][t][3]);
                rs[u] += (p0 + p1) + (p2 + p3);
                ushort4 pk;
                pk.x = f2b(p0); pk.y = f2b(p1); pk.z = f2b(p2); pk.w = f2b(p3);
                int c = t * 2 + (quad >> 1);            // key chunk 0..7
                int addr = l16 * 64 + ((c ^ sw) * 8) + (quad & 1) * 4;
                *(ushort4*)&Plds[wave][u][addr] = pk;
            }
        }

        // P A-frags (q = l16, key chunk = hf*4+quad, swizzled)
        short8v pa[2][2];
        #pragma unroll
        for (int u = 0; u < 2; ++u) {
            pa[u][0] = *(const short8v*)&Plds[wave][u][l16 * 64 + ((quad ^ sw) * 8)];
            pa[u][1] = *(const short8v*)&Plds[wave][u][l16 * 64 + (((4 + quad) ^ sw) * 8)];
        }

        // PV: O[q][d]
        #pragma unroll
        for (int t2 = 0; t2 < 4; ++t2) {
            short8v vf0 = *(const short8v*)&Vb_[quad * 512 + (t2 * 16 + l16) * 8];
            short8v vf1 = *(const short8v*)&Vb_[(4 + quad) * 512 + (t2 * 16 + l16) * 8];
            #pragma unroll
            for (int u = 0; u < 2; ++u) {
                o[u][t2] = __builtin_amdgcn_mfma_f32_16x16x32_bf16(
                    pa[u][0], vf0, o[u][t2], 0, 0, 0);
                o[u][t2] = __builtin_amdgcn_mfma_f32_16x16x32_bf16(
                    pa[u][1], vf1, o[u][t2], 0, 0, 0);
            }
        }
    }

    // Epilogue: reduce row sums across quads, normalize, tanh, store.
    #pragma unroll
    for (int u = 0; u < 2; ++u) {
        float l = rs[u];
        l += __shfl_xor(l, 16);
        l += __shfl_xor(l, 32);          // lanes with l16==q now hold sum(q)
        #pragma unroll
        for (int r = 0; r < 4; ++r) {
            float lr = __shfl(l, quad * 4 + r);     // sum for q-row quad*4+r
            float inv = 1.0f / lr;
            int q = q0 + u * 16 + quad * 4 + r;
            size_t base = ((size_t)b * Sc_ + q) * Hc + h * DHc;
            #pragma unroll
            for (int t2 = 0; t2 < 4; ++t2)
                out[base + t2 * 16 + l16] = fast_tanh(o[u][t2][r] * inv);
        }
    }
}

extern "C" void kernel_launch(void* const* d_in, const int* in_sizes, int n_in,
                              void* d_out, int out_size, void* d_ws, size_t ws_size,
                              hipStream_t stream) {
    const float* X  = (const float*)d_in[0];
    const float* Wq = (const float*)d_in[1];
    const float* bq = (const float*)d_in[2];
    const float* Wk = (const float*)d_in[3];
    const float* bk = (const float*)d_in[4];
    const float* Wv = (const float*)d_in[5];
    const float* bv = (const float*)d_in[6];
    float* out = (float*)d_out;

    ushort* Qb  = (ushort*)d_ws;
    ushort* Kt  = Qb + (size_t)Mc * Hc;
    ushort* Vt  = Kt + (size_t)Mc * Hc;
    ushort* Xt  = Vt + (size_t)Mc * Hc;
    ushort* Wt  = Xt + (size_t)Mc * Hc;
    float*  bbp = (float*)(Wt + (size_t)Ntot * Hc);

    {
        int total = NXC + NWC + Ntot;
        convert_pack<<<(total + 255) / 256, 256, 0, stream>>>(
            X, Wq, Wk, Wv, bq, bk, bv, Xt, Wt, bbp);
    }

    dim3 g1(Mc / 128, Ntot / 128);   // 128 x 18
    qkv_mfma<<<g1, 256, 0, stream>>>(Xt, Wt, bbp, Qb, Kt, Vt);

    dim3 g2(Sc_ / 128, NHc, Bc);     // 4 x 12 x 32
    attn_mfma<<<g2, 256, 0, stream>>>(Qb, Kt, Vt, out);
}

// Round 5
// 224.945 us; speedup vs baseline: 11.5723x; 1.0538x over previous
//
#include <hip/hip_runtime.h>
#include <hip/hip_bf16.h>
#include <cmath>

// Problem constants
#define Bc   32
#define Sc_  512
#define Hc   768
#define NHc  12
#define DHc  64
#define Mc   (Bc * Sc_)     // 16384 tokens
#define Ntot (3 * Hc)       // 2304 fused output cols (Q|K|V)

// 0.125 (1/sqrt(DH)) * log2(e): folded into Q so softmax is exp2(s)
#define QSCALE 0.18033688011112042f

typedef __attribute__((ext_vector_type(8))) short short8v;   // 8 bf16 (4 VGPRs)
typedef __attribute__((ext_vector_type(8))) unsigned short ushort8v;
typedef __attribute__((ext_vector_type(4))) float f32x4;     // MFMA acc

static __device__ __forceinline__ ushort f2b(float f) {
    __hip_bfloat16 h = __float2bfloat16(f);
    return *reinterpret_cast<ushort*>(&h);
}

// async global->LDS, 16B per lane. HW writes lane i to (wave-uniform lds)+i*16B.
static __device__ __forceinline__ void gl2lds(const ushort* g, ushort* l) {
    __builtin_amdgcn_global_load_lds(
        (const __attribute__((address_space(1))) unsigned int*)g,
        (__attribute__((address_space(3))) unsigned int*)l, 16, 0, 0);
}

// tanh(x) = 1 - 2/(exp2(2x*log2e)+1); exact at +/-inf via rcp(inf)=0
static __device__ __forceinline__ float fast_tanh(float x) {
    float e = __builtin_amdgcn_exp2f(x * 2.885390081777927f);
    return 1.0f - 2.0f * __builtin_amdgcn_rcpf(e + 1.0f);
}

// ---------------------------------------------------------------------------
// Kernel 0 (v2): fp32 -> bf16 tiled repack with COALESCED writes.
//   Layouts (unchanged): Xt [m/128][k/8][m%128][8], Wt [n/128][k/8][n%128][8].
//   Block = one 128-row panel (bx<128: X panel; bx>=128: W panel), grid.y=6
//   splits the 96 k-chunks into 4-pass groups. Per pass (32 cols):
//     read: coalesced fp32 row segments (lane pair = 128 B of one row)
//     LDS:  128 x 36-ushort transpose tile (b64 ops, ~2-way banks)
//     write: lanes = consecutive rows -> contiguous 1 KB/wave stores
// ---------------------------------------------------------------------------
__global__ __launch_bounds__(256) void convert_pack(
    const float* __restrict__ X,
    const float* __restrict__ Wq, const float* __restrict__ Wk,
    const float* __restrict__ Wv,
    const float* __restrict__ bq, const float* __restrict__ bk,
    const float* __restrict__ bv,
    ushort* __restrict__ Xt, ushort* __restrict__ Wt, float* __restrict__ bbp)
{
    const int bx = blockIdx.x;
    const int t  = threadIdx.x;

    __shared__ ushort T[128 * 36];

    const float* base;
    ushort* out;
    if (bx < 128) {
        base = X + (size_t)bx * 128 * Hc;
        out  = Xt + (size_t)bx * (96 * 1024);
    } else {
        int nblk = bx - 128;
        int n0 = nblk * 128;
        int z = n0 / Hc;                  // 768/128=6 panels per projection
        int nn0 = n0 - z * Hc;
        const float* W = (z == 0) ? Wq : (z == 1) ? Wk : Wv;
        base = W + (size_t)nn0 * Hc;
        out  = Wt + (size_t)nblk * (96 * 1024);
    }

    const int row_r = t >> 1, half = t & 1;     // read/LDS-write role
    const int row_w = t & 127, cb = t >> 7;     // LDS-read/global-write role

    for (int pp = 0; pp < 4; ++pp) {
        const int pass = blockIdx.y * 4 + pp;
        const int k0 = pass * 32;
        // read 16 fp32 (coalesced), convert to bf16, stage to LDS
        const float* p = base + (size_t)row_r * Hc + k0 + half * 16;
        float4 f0 = *(const float4*)&p[0];
        float4 f1 = *(const float4*)&p[4];
        float4 f2 = *(const float4*)&p[8];
        float4 f3 = *(const float4*)&p[12];
        int wb = row_r * 36 + half * 16;
        ushort4 u0, u1, u2, u3;
        u0.x = f2b(f0.x); u0.y = f2b(f0.y); u0.z = f2b(f0.z); u0.w = f2b(f0.w);
        u1.x = f2b(f1.x); u1.y = f2b(f1.y); u1.z = f2b(f1.z); u1.w = f2b(f1.w);
        u2.x = f2b(f2.x); u2.y = f2b(f2.y); u2.z = f2b(f2.z); u2.w = f2b(f2.w);
        u3.x = f2b(f3.x); u3.y = f2b(f3.y); u3.z = f2b(f3.z); u3.w = f2b(f3.w);
        *(ushort4*)&T[wb + 0]  = u0;
        *(ushort4*)&T[wb + 4]  = u1;
        *(ushort4*)&T[wb + 8]  = u2;
        *(ushort4*)&T[wb + 12] = u3;
        __syncthreads();
        // write out: 2 chunk-units per thread, rows contiguous across lanes
        #pragma unroll
        for (int u = 0; u < 2; ++u) {
            int c = cb * 2 + u;                   // 0..3 local chunk
            ushort4 lo = *(const ushort4*)&T[row_w * 36 + c * 8];
            ushort4 hi = *(const ushort4*)&T[row_w * 36 + c * 8 + 4];
            ushort8v v;
            *(ushort4*)&v = lo;
            *((ushort4*)&v + 1) = hi;
            *(ushort8v*)&out[(size_t)(pass * 4 + c) * 1024 + row_w * 8] = v;
        }
        __syncthreads();
    }

    if (bx == 0 && blockIdx.y == 0) {
        for (int i = t; i < Ntot; i += 256) {
            int z = i / Hc, nn = i - z * Hc;
            bbp[i] = ((z == 0) ? bq : (z == 1) ? bk : bv)[nn];
        }
    }
}

// ---------------------------------------------------------------------------
// Kernel 1: fused QKV projection, bf16 MFMA (m97 structure, 128x128, BK=32).
// Epilogue layouts (per head, head = (b*NH+h), head stride S*DH = 32768):
//   Qb: [s][d] row-major, values pre-scaled by QSCALE
//   Kt: [kb=s/64][dchunk=d/8][s%64][8]      (A-frag-ready, 16B/lane)
//   Vt: [kb=s/64][keychunk=(s%64)/8][d][8]  (B-frag-ready, 16B/lane)
// ---------------------------------------------------------------------------
__global__ __launch_bounds__(256) void qkv_mfma(
    const ushort* __restrict__ Xt, const ushort* __restrict__ Wt,
    const float* __restrict__ bbp,
    ushort* __restrict__ Qb, ushort* __restrict__ Kt, ushort* __restrict__ Vt)
{
    const int tid = threadIdx.x;
    const int wave = tid >> 6, lane = tid & 63;
    const int quad = lane >> 4, l16 = lane & 15;
    const int wr = wave >> 1, wc = wave & 1;
    const int m0 = blockIdx.x * 128;
    const int n0 = blockIdx.y * 128;

    __shared__ __align__(16) ushort As[4096];
    __shared__ __align__(16) ushort Bs[4096];

    f32x4 acc[4][4];
    #pragma unroll
    for (int i = 0; i < 4; ++i)
        #pragma unroll
        for (int j = 0; j < 4; ++j) acc[i][j] = (f32x4)(0.f);

    const ushort* gA = Xt + (size_t)blockIdx.x * (96 * 1024) + wave * 1024 + lane * 8;
    const ushort* gB = Wt + (size_t)blockIdx.y * (96 * 1024) + wave * 1024 + lane * 8;
    ushort* lA = As + wave * 1024;
    ushort* lB = Bs + wave * 1024;

    for (int t = 0; t < 24; ++t) {
        const ushort* ga = gA + t * 4096;
        const ushort* gb = gB + t * 4096;
        gl2lds(ga,       lA);
        gl2lds(ga + 512, lA + 512);
        gl2lds(gb,       lB);
        gl2lds(gb + 512, lB + 512);
        __syncthreads();

        short8v a[4], b[4];
        #pragma unroll
        for (int i = 0; i < 4; ++i)
            a[i] = *(const short8v*)&As[quad * 1024 + (wr * 64 + i * 16 + l16) * 8];
        #pragma unroll
        for (int j = 0; j < 4; ++j)
            b[j] = *(const short8v*)&Bs[quad * 1024 + (wc * 64 + j * 16 + l16) * 8];
        #pragma unroll
        for (int i = 0; i < 4; ++i)
            #pragma unroll
            for (int j = 0; j < 4; ++j)
                acc[i][j] = __builtin_amdgcn_mfma_f32_16x16x32_bf16(
                    a[i], b[j], acc[i][j], 0, 0, 0);
        __syncthreads();
    }

    // Epilogue. C layout per 16x16 tile: col=l16, row=quad*4+r.
    const int z = n0 / Hc;
    #pragma unroll
    for (int j = 0; j < 4; ++j) {
        const int n  = n0 + wc * 64 + j * 16 + l16;
        const int nn = n - z * Hc;
        const int h  = nn >> 6, d = nn & 63;
        const float bias = bbp[n];
        #pragma unroll
        for (int i = 0; i < 4; ++i) {
            const int mbase = m0 + wr * 64 + i * 16 + quad * 4;   // s = mbase + r
            const int bb = mbase >> 9;
            const int s0 = mbase & 511;
            const size_t head = (size_t)(bb * NHc + h) * (Sc_ * DHc);
            if (z == 0) {
                size_t base = head + (size_t)s0 * DHc + d;
                #pragma unroll
                for (int r = 0; r < 4; ++r)
                    Qb[base + (size_t)r * DHc] = f2b((acc[i][j][r] + bias) * QSCALE);
            } else if (z == 1) {
                size_t base = head + (s0 >> 6) * 4096 + (d >> 3) * 512
                            + (s0 & 63) * 8 + (d & 7);
                #pragma unroll
                for (int r = 0; r < 4; ++r)
                    Kt[base + r * 8] = f2b(acc[i][j][r] + bias);
            } else {
                size_t base = head + (s0 >> 6) * 4096 + ((s0 & 63) >> 3) * 512
                            + d * 8 + (s0 & 7);
                ushort4 o;
                o.x = f2b(acc[i][j][0] + bias);
                o.y = f2b(acc[i][j][1] + bias);
                o.z = f2b(acc[i][j][2] + bias);
                o.w = f2b(acc[i][j][3] + bias);
                *(ushort4*)&Vt[base] = o;
            }
        }
    }
}

// ---------------------------------------------------------------------------
// Kernel 2: attention, no-max softmax (p = exp2(s~), scale folded into Q).
//   1-D grid with XCD-aware swizzle: within a 32-block supergroup,
//   bid%8 = head-in-group (== XCD under round-robin), bid>>3 & 3 = q-tile,
//   so all 4 q-tiles of a head share one XCD's L2 for K/V.
// ---------------------------------------------------------------------------
__global__ __launch_bounds__(256) void attn_mfma(
    const ushort* __restrict__ Qb, const ushort* __restrict__ Kt,
    const ushort* __restrict__ Vt, float* __restrict__ out)
{
    const int bid = blockIdx.x;
    const int super = bid >> 5, l = bid & 31;
    const int head_lin = super * 8 + (l & 7);     // 0..383
    const int qt = l >> 3;                        // 0..3
    const int b = head_lin / NHc, h = head_lin % NHc;

    const int wave = threadIdx.x >> 6;
    const int lane = threadIdx.x & 63;
    const int quad = lane >> 4, l16 = lane & 15;
    const int q0 = qt * 128 + wave * 32;
    const int sw = l16 & 7;                       // XOR swizzle key

    const size_t head = (size_t)head_lin * (Sc_ * DHc);
    const ushort* __restrict__ Q = Qb + head;
    const ushort* __restrict__ K = Kt + head;
    const ushort* __restrict__ V = Vt + head;

    __shared__ __align__(16) ushort Plds[4][2][1024];   // wave-private

    short8v aq[2][2];
    #pragma unroll
    for (int u = 0; u < 2; ++u)
        #pragma unroll
        for (int hf = 0; hf < 2; ++hf)
            aq[u][hf] = *(const short8v*)
                &Q[(size_t)(q0 + u * 16 + l16) * DHc + hf * 32 + quad * 8];

    f32x4 o[2][4];
    #pragma unroll
    for (int u = 0; u < 2; ++u)
        #pragma unroll
        for (int t = 0; t < 4; ++t) o[u][t] = (f32x4)(0.f);
    float rs[2] = {0.f, 0.f};

    for (int kb = 0; kb < 8; ++kb) {
        const ushort* Kb_ = K + kb * 4096;
        const ushort* Vb_ = V + kb * 4096;

        short8v kf[4][2];
        #pragma unroll
        for (int t = 0; t < 4; ++t) {
            kf[t][0] = *(const short8v*)&Kb_[quad * 512 + (t * 16 + l16) * 8];
            kf[t][1] = *(const short8v*)&Kb_[(4 + quad) * 512 + (t * 16 + l16) * 8];
        }

        f32x4 sa[2][4];
        #pragma unroll
        for (int u = 0; u < 2; ++u)
            #pragma unroll
            for (int t = 0; t < 4; ++t) {
                f32x4 s = __builtin_amdgcn_mfma_f32_16x16x32_bf16(
                    kf[t][0], aq[u][0], (f32x4)(0.f), 0, 0, 0);
                sa[u][t] = __builtin_amdgcn_mfma_f32_16x16x32_bf16(
                    kf[t][1], aq[u][1], s, 0, 0, 0);
            }

        #pragma unroll
        for (int u = 0; u < 2; ++u) {
            #pragma unroll
            for (int t = 0; t < 4; ++t) {
                float p0 = __builtin_amdgcn_exp2f(sa[u][t][0]);
                float p1 = __builtin_amdgcn_exp2f(sa[u][t][1]);
                float p2 = __builtin_amdgcn_exp2f(sa[u][t][2]);
                float p3 = __builtin_amdgcn_exp2f(sa[u][t][3]);
                rs[u] += (p0 + p1) + (p2 + p3);
                ushort4 pk;
                pk.x = f2b(p0); pk.y = f2b(p1); pk.z = f2b(p2); pk.w = f2b(p3);
                int c = t * 2 + (quad >> 1);            // key chunk 0..7
                int addr = l16 * 64 + ((c ^ sw) * 8) + (quad & 1) * 4;
                *(ushort4*)&Plds[wave][u][addr] = pk;
            }
        }

        short8v pa[2][2];
        #pragma unroll
        for (int u = 0; u < 2; ++u) {
            pa[u][0] = *(const short8v*)&Plds[wave][u][l16 * 64 + ((quad ^ sw) * 8)];
            pa[u][1] = *(const short8v*)&Plds[wave][u][l16 * 64 + (((4 + quad) ^ sw) * 8)];
        }

        #pragma unroll
        for (int t2 = 0; t2 < 4; ++t2) {
            short8v vf0 = *(const short8v*)&Vb_[quad * 512 + (t2 * 16 + l16) * 8];
            short8v vf1 = *(const short8v*)&Vb_[(4 + quad) * 512 + (t2 * 16 + l16) * 8];
            #pragma unroll
            for (int u = 0; u < 2; ++u) {
                o[u][t2] = __builtin_amdgcn_mfma_f32_16x16x32_bf16(
                    pa[u][0], vf0, o[u][t2], 0, 0, 0);
                o[u][t2] = __builtin_amdgcn_mfma_f32_16x16x32_bf16(
                    pa[u][1], vf1, o[u][t2], 0, 0, 0);
            }
        }
    }

    // Epilogue: reduce row sums across quads, normalize, tanh, store.
    #pragma unroll
    for (int u = 0; u < 2; ++u) {
        float l2 = rs[u];
        l2 += __shfl_xor(l2, 16);
        l2 += __shfl_xor(l2, 32);        // lanes with l16==q now hold sum(q)
        #pragma unroll
        for (int r = 0; r < 4; ++r) {
            float lr = __shfl(l2, quad * 4 + r);    // sum for q-row quad*4+r
            float inv = 1.0f / lr;
            int q = q0 + u * 16 + quad * 4 + r;
            size_t base = ((size_t)b * Sc_ + q) * Hc + h * DHc;
            #pragma unroll
            for (int t2 = 0; t2 < 4; ++t2)
                out[base + t2 * 16 + l16] = fast_tanh(o[u][t2][r] * inv);
        }
    }
}

extern "C" void kernel_launch(void* const* d_in, const int* in_sizes, int n_in,
                              void* d_out, int out_size, void* d_ws, size_t ws_size,
                              hipStream_t stream) {
    const float* X  = (const float*)d_in[0];
    const float* Wq = (const float*)d_in[1];
    const float* bq = (const float*)d_in[2];
    const float* Wk = (const float*)d_in[3];
    const float* bk = (const float*)d_in[4];
    const float* Wv = (const float*)d_in[5];
    const float* bv = (const float*)d_in[6];
    float* out = (float*)d_out;

    ushort* Qb  = (ushort*)d_ws;
    ushort* Kt  = Qb + (size_t)Mc * Hc;
    ushort* Vt  = Kt + (size_t)Mc * Hc;
    ushort* Xt  = Vt + (size_t)Mc * Hc;
    ushort* Wt  = Xt + (size_t)Mc * Hc;
    float*  bbp = (float*)(Wt + (size_t)Ntot * Hc);

    dim3 g0(146, 6);                 // 128 X panels + 18 W panels, 6 k-slices
    convert_pack<<<g0, 256, 0, stream>>>(X, Wq, Wk, Wv, bq, bk, bv, Xt, Wt, bbp);

    dim3 g1(Mc / 128, Ntot / 128);   // 128 x 18
    qkv_mfma<<<g1, 256, 0, stream>>>(Xt, Wt, bbp, Qb, Kt, Vt);

    attn_mfma<<<dim3(1536), 256, 0, stream>>>(Qb, Kt, Vt, out);
}